// Round 11
// baseline (183.212 us; speedup 1.0000x reference)
//
#include <hip/hip_runtime.h>
#include <cmath>

#define NB 2
#define NT 32
#define NH 65
#define NW 65
#define NC 32
#define NF 32
#define NKS 15
#define NHP 33
#define NWP 33
#define NWR 33
#define NWOUT 64
#define PI_F 3.14159265358979323846f

using bf16x8 = __attribute__((ext_vector_type(8))) __bf16;
using f32x4  = __attribute__((ext_vector_type(4))) float;
using s16x4  = __attribute__((ext_vector_type(4))) short;

__device__ inline unsigned short f2bf(float v) {
    unsigned u = __float_as_uint(v);
    u = u + 0x7FFF + ((u >> 16) & 1);
    return (unsigned short)(u >> 16);
}
__device__ inline float bf2f(unsigned short h) {
    return __uint_as_float((unsigned)h << 16);
}

union FragU { s16x4 h[2]; bf16x8 v; };

// ---------------- setup (fused): twiddle tables + conv weights + spectra +
// DFT-matrix bf16 hi/lo A-fragment tables.
// blk 0..9: small tables; 10..45: conv weights; 46..314: KE/KI spectra;
// 315..494: A-tables [6 tbl][5 mt][3 kt][64 lane][8 e]
//   tbl 0/1: cos hi/lo; 2/3: +sin hi/lo; 4/5: -sin hi/lo;
//   element = M[mt*16+(lane&15)][kt*32+(lane>>4)*8+e], 0 outside 65x65.
__global__ __launch_bounds__(256) void setup_kernel(
    const float* __restrict__ w, unsigned short* __restrict__ wBh,
    unsigned short* __restrict__ wBl,
    float2* __restrict__ twr, float2* __restrict__ twi,
    const float* __restrict__ kexc, const float* __restrict__ kinh,
    float2* __restrict__ KE, float2* __restrict__ KI,
    unsigned short* __restrict__ Atab)
{
    int blk = blockIdx.x;
    if (blk < 10) {
        int tid = blk * 256 + threadIdx.x;
        if (tid < NH * 36) {
            int q = tid / 36, wr = tid % 36;
            float2 v = make_float2(0.f, 0.f);
            if (wr < NWR) {
                int p = (q * wr) % NH;
                float a = -2.f * PI_F * (float)p / (float)NH;
                v = make_float2(cosf(a), sinf(a));
            }
            twr[tid] = v;
        }
        if (tid < 31 * 64) {
            int q = tid / 64 + 1, ow = tid % 64;
            int p = (q * ow) & 63;
            float a = 2.f * PI_F * (float)p / (float)NWOUT;
            twi[tid] = make_float2(cosf(a), sinf(a));
        }
    } else if (blk < 46) {
        int tid = (blk - 10) * 256 + threadIdx.x;
        if (tid < 9 * NF * NC) {
            int dd = tid / 1024;
            int f = (tid / 32) % 32;
            int c = tid % 32;
            float v = w[((size_t)dd * NC + c) * NF + f];
            unsigned short h = f2bf(v);
            wBh[tid] = h;
            wBl[tid] = f2bf(v - bf2f(h));
        }
    } else if (blk < 315) {
        __shared__ float2 tw[NH];
        int tid = threadIdx.x;
        if (tid < NH) {
            float a = -2.f * PI_F * (float)tid / (float)NH;
            tw[tid] = make_float2(cosf(a), sinf(a));
        }
        __syncthreads();
        int idx = (blk - 46) * 256 + tid;
        if (idx >= NH * NWR * NC) return;
        int c = idx % NC;
        int rem = idx / NC;
        int wr = rem % NWR;
        int h = rem / NWR;
        float ker = 0, kei = 0, kir = 0, kii = 0;
        int prow = (25 * (h + wr)) % NH;
        for (int i = 0; i < NKS; ++i) {
            int p = prow;
            for (int j = 0; j < NKS; ++j) {
                float2 e = tw[p];
                float ve = kexc[(i * NKS + j) * NC + c];
                float vi = kinh[(i * NKS + j) * NC + c];
                ker = fmaf(ve, e.x, ker); kei = fmaf(ve, e.y, kei);
                kir = fmaf(vi, e.x, kir); kii = fmaf(vi, e.y, kii);
                p += wr; if (p >= NH) p -= NH;
            }
            prow += h; if (prow >= NH) prow -= NH;
        }
        KE[idx] = make_float2(ker, kei);
        KI[idx] = make_float2(kir, kii);
    } else {
        int idx = (blk - 315) * 256 + threadIdx.x;   // < 46080
        if (idx >= 46080) return;
        int tbl = idx / 7680;
        int rem = idx % 7680;
        int mt = rem / 1536;
        int rem2 = rem % 1536;
        int kt = rem2 / 512;
        int rem3 = rem2 % 512;
        int lane = rem3 / 8;
        int e = rem3 % 8;
        int m = mt * 16 + (lane & 15);
        int k = kt * 32 + (lane >> 4) * 8 + e;
        unsigned short out = 0;
        if (m < NH && k < NH) {
            float a = 2.f * PI_F * (float)((m * k) % NH) / (float)NH;
            float base = (tbl < 2) ? cosf(a) : ((tbl < 4) ? sinf(a) : -sinf(a));
            unsigned short hi = f2bf(base);
            out = (tbl & 1) ? f2bf(base - bf2f(hi)) : hi;
        }
        Atab[idx] = out;
    }
}

// ---------------- Kernel A: conv3x3 stride2 SAME + bias + gelu via MFMA
__global__ __launch_bounds__(256) void conv_mfma_kernel(
    const float* __restrict__ x, const unsigned short* __restrict__ wBh,
    const unsigned short* __restrict__ wBl, const float* __restrict__ bias,
    float* __restrict__ partial)
{
    __shared__ unsigned short aH[3 * 68 * 36];
    __shared__ unsigned short aL[3 * 68 * 36];
    int blk = blockIdx.x;              // (b*NT+t)*NHP + i
    int i = blk % NHP;
    int bt = blk / NHP;
    int tid = threadIdx.x;
    int l = tid & 63;
    int w = tid >> 6;

    int nt = w & 1;
    int fcol = nt * 16 + (l & 15);
    int c0 = (l >> 4) * 8;
    bf16x8 bh[9], bl[9];
    #pragma unroll
    for (int dd = 0; dd < 9; ++dd) {
        bh[dd] = *(const bf16x8*)(wBh + dd * 1024 + fcol * 32 + c0);
        bl[dd] = *(const bf16x8*)(wBl + dd * 1024 + fcol * 32 + c0);
    }

    const float* xb = x + (size_t)bt * (NH * NW * NC);
    for (int q = tid; q < 3 * 68 * 8; q += 256) {
        int r = q / 544;
        int k = q % 544;
        int pcol = k >> 3;
        int c4 = (k & 7) * 4;
        int gr = 2 * i - 1 + r;
        int gcol = pcol - 1;
        float4 v = make_float4(0.f, 0.f, 0.f, 0.f);
        if (gr >= 0 && gr < NH && gcol >= 0 && gcol < NW)
            v = *(const float4*)(xb + ((size_t)gr * NW + gcol) * NC + c4);
        int base = (r * 68 + pcol) * 36 + c4;
        unsigned short h0 = f2bf(v.x), h1 = f2bf(v.y), h2 = f2bf(v.z), h3 = f2bf(v.w);
        s16x4 th = {(short)h0, (short)h1, (short)h2, (short)h3};
        *(s16x4*)(aH + base) = th;
        s16x4 tl = {(short)f2bf(v.x - bf2f(h0)), (short)f2bf(v.y - bf2f(h1)),
                    (short)f2bf(v.z - bf2f(h2)), (short)f2bf(v.w - bf2f(h3))};
        *(s16x4*)(aL + base) = tl;
    }
    __syncthreads();

    float bv = bias[fcol];
    f32x4 acc0 = {bv, bv, bv, bv};
    f32x4 acc1 = {bv, bv, bv, bv};
    const int mtA = (w >> 1) ? 1 : 0;
    const bool hasB = (w >> 1) == 0;
    int m15 = l & 15;

    #pragma unroll
    for (int dd = 0; dd < 9; ++dd) {
        const int di = dd / 3, dj = dd % 3;
        {
            int pcol = 2 * (mtA * 16 + m15) + dj;
            int off = (di * 68 + pcol) * 36 + c0;
            FragU ah, al;
            ah.h[0] = *(const s16x4*)(aH + off);
            ah.h[1] = *(const s16x4*)(aH + off + 4);
            al.h[0] = *(const s16x4*)(aL + off);
            al.h[1] = *(const s16x4*)(aL + off + 4);
            acc0 = __builtin_amdgcn_mfma_f32_16x16x32_bf16(al.v, bh[dd], acc0, 0, 0, 0);
            acc0 = __builtin_amdgcn_mfma_f32_16x16x32_bf16(ah.v, bl[dd], acc0, 0, 0, 0);
            acc0 = __builtin_amdgcn_mfma_f32_16x16x32_bf16(ah.v, bh[dd], acc0, 0, 0, 0);
        }
        if (hasB) {
            int pcol = 2 * (32 + m15) + dj;
            if (pcol > 67) pcol = 67;
            int off = (di * 68 + pcol) * 36 + c0;
            FragU ah, al;
            ah.h[0] = *(const s16x4*)(aH + off);
            ah.h[1] = *(const s16x4*)(aH + off + 4);
            al.h[0] = *(const s16x4*)(aL + off);
            al.h[1] = *(const s16x4*)(aL + off + 4);
            acc1 = __builtin_amdgcn_mfma_f32_16x16x32_bf16(al.v, bh[dd], acc1, 0, 0, 0);
            acc1 = __builtin_amdgcn_mfma_f32_16x16x32_bf16(ah.v, bl[dd], acc1, 0, 0, 0);
            acc1 = __builtin_amdgcn_mfma_f32_16x16x32_bf16(ah.v, bh[dd], acc1, 0, 0, 0);
        }
    }

    float* pout = partial + (size_t)blk * (NWP * NF);
    int g4 = (l >> 4) * 4;
    #define GELU(v) (0.5f * (v) * (1.f + tanhf(0.7978845608028654f * ((v) + 0.044715f * (v) * (v) * (v)))))
    #pragma unroll
    for (int r = 0; r < 4; ++r) {
        float v = acc0[r];
        pout[(mtA * 16 + g4 + r) * NF + fcol] = GELU(v);
    }
    if (hasB && g4 == 0) {
        float v = acc1[0];
        pout[32 * NF + fcol] = GELU(v);
    }
    #undef GELU
}

// ---------------- ctx reduce stage 1
__global__ __launch_bounds__(256) void ctx_reduce1_kernel(
    const float* __restrict__ partial, float* __restrict__ red2)
{
    __shared__ float red[4][64];
    int blk = blockIdx.x;
    int b = blk / 136;
    int rem = blk % 136;
    int chunk = rem / 8;
    int ts = rem % 8;
    int lane = threadIdx.x & 63;
    int tig = threadIdx.x >> 6;
    int jf = chunk * 64 + lane;
    float s0 = 0.f, s1 = 0.f, s2 = 0.f;
    if (jf < NWP * NF) {
        const float* p = partial + (size_t)b * (NT * NHP) * (NWP * NF)
                       + (size_t)(ts * 132 + tig * 33) * (NWP * NF) + jf;
        #pragma unroll 3
        for (int s = 0; s < 33; s += 3) {
            s0 += p[(size_t)s * (NWP * NF)];
            s1 += p[(size_t)(s + 1) * (NWP * NF)];
            s2 += p[(size_t)(s + 2) * (NWP * NF)];
        }
    }
    red[tig][lane] = s0 + s1 + s2;
    __syncthreads();
    if (threadIdx.x < 64) {
        float tot = red[0][threadIdx.x] + red[1][threadIdx.x] +
                    red[2][threadIdx.x] + red[3][threadIdx.x];
        red2[((b * 17 + chunk) * 8 + ts) * 64 + threadIdx.x] = tot;
    }
}

// ---------------- ctx reduce stage 2
__global__ __launch_bounds__(256) void ctx_reduce2_kernel(
    const float* __restrict__ red2, float* __restrict__ ctx)
{
    __shared__ float red[4][64];
    int b = blockIdx.x / 17, chunk = blockIdx.x % 17;
    int lane = threadIdx.x & 63, tg = threadIdx.x >> 6;
    const float* r2 = red2 + ((size_t)(b * 17 + chunk) * 8) * 64;
    float v = r2[(2 * tg) * 64 + lane] + r2[(2 * tg + 1) * 64 + lane];
    red[tg][lane] = v;
    __syncthreads();
    if (threadIdx.x < 64) {
        int jf = chunk * 64 + threadIdx.x;
        if (jf < NWP * NF) {
            float tot = red[0][threadIdx.x] + red[1][threadIdx.x] +
                        red[2][threadIdx.x] + red[3][threadIdx.x];
            ctx[b * (NWP * NF) + jf] = tot * (1.f / (NT * NHP));
        }
    }
}

// ---------------- Kernel B: gates
__global__ __launch_bounds__(256) void gate_kernel(
    const float* __restrict__ ctx,
    const float* __restrict__ wA, const float* __restrict__ bA,
    const float* __restrict__ wD, const float* __restrict__ bD,
    const float* __restrict__ wM, const float* __restrict__ bM,
    const float* __restrict__ wG, const float* __restrict__ bG,
    float* __restrict__ alpha, float* __restrict__ delta,
    float* __restrict__ mu, float* __restrict__ gamma)
{
    int idx = blockIdx.x * 256 + threadIdx.x;
    if (idx >= NB * NWP * NC) return;
    int c = idx % NC;
    int bw = idx / NC;
    float sA = bA[c], sD = bD[c], sM = bM[c], sG = bG[c];
    #pragma unroll
    for (int f = 0; f < NF; ++f) {
        float v = ctx[bw * NF + f];
        sA = fmaf(v, wA[f * NC + c], sA);
        sD = fmaf(v, wD[f * NC + c], sD);
        sM = fmaf(v, wM[f * NC + c], sM);
        sG = fmaf(v, wG[f * NC + c], sG);
    }
    alpha[idx] = 1.f / (1.f + expf(-sA));
    delta[idx] = 1.f / (1.f + expf(-sD));
    mu[idx]    = fmaxf(sM, 0.f) + log1pf(expf(-fabsf(sM)));
    gamma[idx] = fmaxf(sG, 0.f) + log1pf(expf(-fabsf(sG)));
}

// ---------------- Kernel D: rDFT along W (65 -> 33), 4 h-rows per block
__global__ __launch_bounds__(256) void dft_rows_kernel(
    const float* __restrict__ x, const float2* __restrict__ twr_g,
    float2* __restrict__ U1)
{
    __shared__ __align__(16) float row[4][NW * NC];   // 33.3 KB
    __shared__ __align__(16) float2 twt[NH * 36];     // 18.7 KB
    int tid = threadIdx.x;
    int blk = blockIdx.x;           // bt*17 + grp
    int grp = blk % 17;
    int bt = blk / 17;
    int hbase = grp * 4;
    int nrows = NH - hbase; if (nrows > 4) nrows = 4;

    const float* xp = x + ((size_t)bt * NH + hbase) * (NW * NC);
    for (int idx = tid; idx < nrows * NW * NC; idx += 256) ((float*)row)[idx] = xp[idx];
    for (int idx = tid; idx < NH * 36; idx += 256) twt[idx] = twr_g[idx];
    __syncthreads();

    int c = tid & 31;
    int jg = tid >> 5;
    float2 acc[4][4];
    #pragma unroll
    for (int r = 0; r < 4; ++r)
        #pragma unroll
        for (int k = 0; k < 4; ++k) acc[r][k] = make_float2(0.f, 0.f);

    const float2* tp = twt + 4 * jg;
    #pragma unroll 5
    for (int q = 0; q < NW; ++q) {
        float4 e01 = *(const float4*)&tp[q * 36];
        float4 e23 = *(const float4*)&tp[q * 36 + 2];
        #pragma unroll
        for (int r = 0; r < 4; ++r) {
            float v = row[r][q * NC + c];
            acc[r][0].x = fmaf(v, e01.x, acc[r][0].x); acc[r][0].y = fmaf(v, e01.y, acc[r][0].y);
            acc[r][1].x = fmaf(v, e01.z, acc[r][1].x); acc[r][1].y = fmaf(v, e01.w, acc[r][1].y);
            acc[r][2].x = fmaf(v, e23.x, acc[r][2].x); acc[r][2].y = fmaf(v, e23.y, acc[r][2].y);
            acc[r][3].x = fmaf(v, e23.z, acc[r][3].x); acc[r][3].y = fmaf(v, e23.w, acc[r][3].y);
        }
    }
    #pragma unroll
    for (int r = 0; r < 4; ++r) {
        if (r < nrows) {
            float2* up = U1 + ((size_t)bt * NH + hbase + r) * (NWR * NC);
            up[(4 * jg + 0) * NC + c] = acc[r][0];
            up[(4 * jg + 1) * NC + c] = acc[r][1];
            up[(4 * jg + 2) * NC + c] = acc[r][2];
            up[(4 * jg + 3) * NC + c] = acc[r][3];
        }
    }
    if (jg == 0) {   // wr = 32
        float2 a32[4];
        #pragma unroll
        for (int r = 0; r < 4; ++r) a32[r] = make_float2(0.f, 0.f);
        #pragma unroll 5
        for (int q = 0; q < NW; ++q) {
            float2 e = twt[q * 36 + 32];
            #pragma unroll
            for (int r = 0; r < 4; ++r) {
                float v = row[r][q * NC + c];
                a32[r].x = fmaf(v, e.x, a32[r].x);
                a32[r].y = fmaf(v, e.y, a32[r].y);
            }
        }
        #pragma unroll
        for (int r = 0; r < 4; ++r)
            if (r < nrows)
                U1[((size_t)bt * NH + hbase + r) * (NWR * NC) + 32 * NC + c] = a32[r];
    }
}

// ---------------- Kernel E/G: 65-pt DFT along H via MFMA (bf16 hi/lo).
// Per block (bt, wr): Y[65,32] = M[65x65] . X[65,32] complex, as 4 real
// matmuls on the matrix pipe. DIR=0 fwd, DIR=1 inverse (scale 1/65).
template <int DIR>
__global__ __launch_bounds__(256) void dft_cols_mfma_kernel(
    const float2* __restrict__ in, float2* __restrict__ out,
    const unsigned short* __restrict__ Atab)
{
    __shared__ __align__(16) unsigned short Xt[4][32][104];  // Xr_h, Xr_l, Xi_h, Xi_l
    int tid = threadIdx.x;
    int blk = blockIdx.x;
    int wr = blk % NWR;
    int bt = blk / NWR;
    const float2* ip = in + ((size_t)bt * NH) * (NWR * NC) + wr * NC;

    for (int idx = tid; idx < 96 * 32; idx += 256) {
        int p = idx >> 5, c = idx & 31;
        float2 v = make_float2(0.f, 0.f);
        if (p < NH) v = ip[(size_t)p * (NWR * NC) + c];
        unsigned short rh = f2bf(v.x);
        unsigned short ih = f2bf(v.y);
        Xt[0][c][p] = rh;
        Xt[1][c][p] = f2bf(v.x - bf2f(rh));
        Xt[2][c][p] = ih;
        Xt[3][c][p] = f2bf(v.y - bf2f(ih));
    }
    __syncthreads();

    int l = tid & 63;
    int w = tid >> 6;
    int lm = l & 15;
    int lk = (l >> 4) * 8;
    const float scale = DIR ? (1.f / (float)NH) : 1.f;
    float2* op = out + ((size_t)bt * NH) * (NWR * NC) + wr * NC;

    for (int pr = w; pr < 10; pr += 4) {
        int mt = pr >> 1, nt = pr & 1;
        f32x4 accr = {0.f, 0.f, 0.f, 0.f};
        f32x4 acci = {0.f, 0.f, 0.f, 0.f};
        #pragma unroll
        for (int kt = 0; kt < 3; ++kt) {
            const unsigned short* ab = Atab + ((size_t)mt * 3 + kt) * 512 + l * 8;
            bf16x8 Ch  = *(const bf16x8*)(ab + 0 * 7680);
            bf16x8 Cl  = *(const bf16x8*)(ab + 1 * 7680);
            bf16x8 Sph = *(const bf16x8*)(ab + 2 * 7680);
            bf16x8 Spl = *(const bf16x8*)(ab + 3 * 7680);
            bf16x8 Snh = *(const bf16x8*)(ab + 4 * 7680);
            bf16x8 Snl = *(const bf16x8*)(ab + 5 * 7680);
            // fwd: Yr = C.Xr + Sp.Xi ; Yi = C.Xi + Sn.Xr.  inv: swap Sp<->Sn.
            bf16x8 S1h = DIR ? Snh : Sph, S1l = DIR ? Snl : Spl;
            bf16x8 S2h = DIR ? Sph : Snh, S2l = DIR ? Spl : Snl;
            int n = nt * 16 + lm;
            int k = kt * 32 + lk;
            bf16x8 Xrh = *(const bf16x8*)&Xt[0][n][k];
            bf16x8 Xrl = *(const bf16x8*)&Xt[1][n][k];
            bf16x8 Xih = *(const bf16x8*)&Xt[2][n][k];
            bf16x8 Xil = *(const bf16x8*)&Xt[3][n][k];
            accr = __builtin_amdgcn_mfma_f32_16x16x32_bf16(Cl,  Xrh, accr, 0, 0, 0);
            accr = __builtin_amdgcn_mfma_f32_16x16x32_bf16(Ch,  Xrl, accr, 0, 0, 0);
            accr = __builtin_amdgcn_mfma_f32_16x16x32_bf16(Ch,  Xrh, accr, 0, 0, 0);
            accr = __builtin_amdgcn_mfma_f32_16x16x32_bf16(S1l, Xih, accr, 0, 0, 0);
            accr = __builtin_amdgcn_mfma_f32_16x16x32_bf16(S1h, Xil, accr, 0, 0, 0);
            accr = __builtin_amdgcn_mfma_f32_16x16x32_bf16(S1h, Xih, accr, 0, 0, 0);
            acci = __builtin_amdgcn_mfma_f32_16x16x32_bf16(Cl,  Xih, acci, 0, 0, 0);
            acci = __builtin_amdgcn_mfma_f32_16x16x32_bf16(Ch,  Xil, acci, 0, 0, 0);
            acci = __builtin_amdgcn_mfma_f32_16x16x32_bf16(Ch,  Xih, acci, 0, 0, 0);
            acci = __builtin_amdgcn_mfma_f32_16x16x32_bf16(S2l, Xrh, acci, 0, 0, 0);
            acci = __builtin_amdgcn_mfma_f32_16x16x32_bf16(S2h, Xrl, acci, 0, 0, 0);
            acci = __builtin_amdgcn_mfma_f32_16x16x32_bf16(S2h, Xrh, acci, 0, 0, 0);
        }
        int c = nt * 16 + lm;
        #pragma unroll
        for (int r = 0; r < 4; ++r) {
            int m = mt * 16 + (l >> 4) * 4 + r;
            if (m < NH)
                op[(size_t)m * (NWR * NC) + c] =
                    make_float2(accr[r] * scale, acci[r] * scale);
        }
    }
}

// ---------------- Kernel F: SSM scan over T
__global__ __launch_bounds__(256) void scan_kernel(
    float2* __restrict__ buf, const float2* __restrict__ KE,
    const float2* __restrict__ KI, const float* __restrict__ alpha,
    const float* __restrict__ delta, const float* __restrict__ mu,
    const float* __restrict__ gamma)
{
    int idx = blockIdx.x * 256 + threadIdx.x;
    if (idx >= NB * NH * NWR * NC) return;
    int c = idx % NC;
    int rem = idx / NC;
    int wr = rem % NWR;
    int rem2 = rem / NWR;
    int h = rem2 % NH;
    int b = rem2 / NH;

    int gi = (b * NWP + wr) * NC + c;
    float axx = 0.9f * alpha[gi];
    float ayy = 0.9f * delta[gi];
    float m = mu[gi], g = gamma[gi];
    float2 ki = KI[(h * NWR + wr) * NC + c];
    float2 ke = KE[(h * NWR + wr) * NC + c];
    float2 axy = make_float2(-ki.x * m, -ki.y * m);
    float2 ayx = make_float2(ke.x * g, ke.y * g);

    float2 xs = make_float2(0.f, 0.f), ys = make_float2(0.f, 0.f);
    size_t base = ((size_t)b * NT) * NH * NWR * NC + (size_t)h * (NWR * NC) + wr * NC + c;
    const size_t stride = (size_t)NH * NWR * NC;
    for (int t = 0; t < NT; ++t) {
        float2 U = buf[base + (size_t)t * stride];
        float2 nx, ny;
        nx.x = fmaf(axx, xs.x, fmaf(axy.x, ys.x, fmaf(-axy.y, ys.y, U.x)));
        nx.y = fmaf(axx, xs.y, fmaf(axy.x, ys.y, fmaf(axy.y, ys.x, U.y)));
        ny.x = fmaf(ayx.x, xs.x, fmaf(-ayx.y, xs.y, ayy * ys.x));
        ny.y = fmaf(ayx.x, xs.y, fmaf(ayx.y, xs.x, ayy * ys.y));
        xs = nx; ys = ny;
        buf[base + (size_t)t * stride] = ys;
    }
}

// ---------------- Kernel H: irfft along W (33 -> 64), 4 h-rows per block
__global__ __launch_bounds__(256) void irfft_w_kernel(
    const float2* __restrict__ Z, const float2* __restrict__ twi_g,
    float* __restrict__ out)
{
    __shared__ __align__(16) float2 z[4][NWR * NC];   // 33.8 KB
    __shared__ __align__(16) float2 twi[31 * 64];     // 15.9 KB
    int tid = threadIdx.x;
    int blk = blockIdx.x;           // bt*17 + grp
    int grp = blk % 17;
    int bt = blk / 17;
    int hbase = grp * 4;
    int nrows = NH - hbase; if (nrows > 4) nrows = 4;

    const float2* zp = Z + ((size_t)bt * NH + hbase) * (NWR * NC);
    for (int idx = tid; idx < nrows * NWR * NC; idx += 256) ((float2*)z)[idx] = zp[idx];
    for (int idx = tid; idx < 31 * 64; idx += 256) twi[idx] = twi_g[idx];
    __syncthreads();

    int c = tid & 31;
    int g = tid >> 5;
    float acc[4][8];
    #pragma unroll
    for (int r = 0; r < 4; ++r) {
        float z0 = z[r][c].x;
        float zn = z[r][32 * NC + c].x;
        #pragma unroll
        for (int m = 0; m < 8; ++m) acc[r][m] = z0 + ((m & 1) ? -zn : zn);
    }
    const float2* tp = twi + 8 * g;
    for (int q = 1; q < 32; ++q) {
        const float4* tq = (const float4*)&tp[(q - 1) * 64];
        float4 e0 = tq[0], e1 = tq[1], e2 = tq[2], e3 = tq[3];
        #pragma unroll
        for (int r = 0; r < 4; ++r) {
            float2 v = z[r][q * NC + c];
            float vx = 2.f * v.x, vy = 2.f * v.y;
            acc[r][0] = fmaf(vx, e0.x, fmaf(-vy, e0.y, acc[r][0]));
            acc[r][1] = fmaf(vx, e0.z, fmaf(-vy, e0.w, acc[r][1]));
            acc[r][2] = fmaf(vx, e1.x, fmaf(-vy, e1.y, acc[r][2]));
            acc[r][3] = fmaf(vx, e1.z, fmaf(-vy, e1.w, acc[r][3]));
            acc[r][4] = fmaf(vx, e2.x, fmaf(-vy, e2.y, acc[r][4]));
            acc[r][5] = fmaf(vx, e2.z, fmaf(-vy, e2.w, acc[r][5]));
            acc[r][6] = fmaf(vx, e3.x, fmaf(-vy, e3.y, acc[r][6]));
            acc[r][7] = fmaf(vx, e3.z, fmaf(-vy, e3.w, acc[r][7]));
        }
    }
    #pragma unroll
    for (int r = 0; r < 4; ++r) {
        if (r < nrows) {
            float* op = out + ((size_t)bt * NH + hbase + r) * (NWOUT * NC);
            #pragma unroll
            for (int m = 0; m < 8; ++m)
                op[(8 * g + m) * NC + c] = acc[r][m] * (1.f / (float)NWOUT);
        }
    }
}

extern "C" void kernel_launch(void* const* d_in, const int* in_sizes, int n_in,
                              void* d_out, int out_size, void* d_ws, size_t ws_size,
                              hipStream_t stream)
{
    const float* x     = (const float*)d_in[0];
    const float* convw = (const float*)d_in[1];
    const float* convb = (const float*)d_in[2];
    const float* wA = (const float*)d_in[3];
    const float* bA = (const float*)d_in[4];
    const float* wD = (const float*)d_in[5];
    const float* bD = (const float*)d_in[6];
    const float* wM = (const float*)d_in[7];
    const float* bM = (const float*)d_in[8];
    const float* wG = (const float*)d_in[9];
    const float* bG = (const float*)d_in[10];
    const float* kexc = (const float*)d_in[11];
    const float* kinh = (const float*)d_in[12];

    const size_t NBIG = (size_t)NB * NT * NH * NWR * NC;
    char* ws = (char*)d_ws;
    float2* bufA    = (float2*)ws;  ws += NBIG * sizeof(float2);
    float2* KE      = (float2*)ws;  ws += (size_t)NH * NWR * NC * sizeof(float2);
    float2* KI      = (float2*)ws;  ws += (size_t)NH * NWR * NC * sizeof(float2);
    float*  partial = (float*)ws;   ws += (size_t)NB * (NT * NHP) * (NWP * NF) * sizeof(float);
    float*  ctx     = (float*)ws;   ws += (size_t)NB * NWP * NF * sizeof(float);
    float*  red2    = (float*)ws;   ws += (size_t)NB * 17 * 8 * 64 * sizeof(float);
    float*  alpha   = (float*)ws;   ws += (size_t)NB * NWP * NC * sizeof(float);
    float*  delta   = (float*)ws;   ws += (size_t)NB * NWP * NC * sizeof(float);
    float*  mu      = (float*)ws;   ws += (size_t)NB * NWP * NC * sizeof(float);
    float*  gamma   = (float*)ws;   ws += (size_t)NB * NWP * NC * sizeof(float);
    float2* TWR     = (float2*)ws;  ws += (size_t)NH * 36 * sizeof(float2);
    float2* TWI     = (float2*)ws;  ws += (size_t)31 * 64 * sizeof(float2);
    unsigned short* wBh = (unsigned short*)ws; ws += (size_t)9 * NC * NF * sizeof(unsigned short);
    unsigned short* wBl = (unsigned short*)ws; ws += (size_t)9 * NC * NF * sizeof(unsigned short);
    unsigned short* Atab = (unsigned short*)ws; ws += (size_t)46080 * sizeof(unsigned short);

    // blocks: 10 tables + 36 weights + 269 spectra + 180 A-tables = 495
    setup_kernel<<<495, 256, 0, stream>>>(
        convw, wBh, wBl, TWR, TWI, kexc, kinh, KE, KI, Atab);

    conv_mfma_kernel<<<NB * NT * NHP, 256, 0, stream>>>(x, wBh, wBl, convb, partial);
    ctx_reduce1_kernel<<<NB * 136, 256, 0, stream>>>(partial, red2);
    ctx_reduce2_kernel<<<NB * 17, 256, 0, stream>>>(red2, ctx);
    gate_kernel<<<(NB * NWP * NC + 255) / 256, 256, 0, stream>>>(
        ctx, wA, bA, wD, bD, wM, bM, wG, bG, alpha, delta, mu, gamma);

    dft_rows_kernel<<<NB * NT * 17, 256, 0, stream>>>(x, TWR, bufA);
    dft_cols_mfma_kernel<0><<<NB * NT * NWR, 256, 0, stream>>>(bufA, bufA, Atab);

    scan_kernel<<<(NB * NH * NWR * NC + 255) / 256, 256, 0, stream>>>(
        bufA, KE, KI, alpha, delta, mu, gamma);

    dft_cols_mfma_kernel<1><<<NB * NT * NWR, 256, 0, stream>>>(bufA, bufA, Atab);
    irfft_w_kernel<<<NB * NT * 17, 256, 0, stream>>>(bufA, TWI, (float*)d_out);
}

// Round 12
// 165.008 us; speedup vs baseline: 1.1103x; 1.1103x over previous
//
#include <hip/hip_runtime.h>
#include <cmath>

#define NB 2
#define NT 32
#define NH 65
#define NW 65
#define NC 32
#define NF 32
#define NKS 15
#define NHP 33
#define NWP 33
#define NWR 33
#define NWOUT 64
#define PI_F 3.14159265358979323846f

using bf16x8 = __attribute__((ext_vector_type(8))) __bf16;
using f32x4  = __attribute__((ext_vector_type(4))) float;
using s16x4  = __attribute__((ext_vector_type(4))) short;

__device__ inline unsigned short f2bf(float v) {
    unsigned u = __float_as_uint(v);
    u = u + 0x7FFF + ((u >> 16) & 1);
    return (unsigned short)(u >> 16);
}
__device__ inline float bf2f(unsigned short h) {
    return __uint_as_float((unsigned)h << 16);
}

union FragU { s16x4 h[2]; bf16x8 v; };

// ---------------- setup (fused): twiddle tables + bf16 hi/lo conv weights +
// kernel spectra. blk 0..9: tables; blk 10..45: weights; blk 46..314: KE/KI.
__global__ __launch_bounds__(256) void setup_kernel(
    const float* __restrict__ w, unsigned short* __restrict__ wBh,
    unsigned short* __restrict__ wBl,
    float2* __restrict__ twr, float2* __restrict__ twb, float2* __restrict__ twi,
    const float* __restrict__ kexc, const float* __restrict__ kinh,
    float2* __restrict__ KE, float2* __restrict__ KI)
{
    int blk = blockIdx.x;
    if (blk < 10) {
        int tid = blk * 256 + threadIdx.x;
        if (tid < NH * 36) {
            int q = tid / 36, wr = tid % 36;
            float2 v = make_float2(0.f, 0.f);
            if (wr < NWR) {
                int p = (q * wr) % NH;
                float a = -2.f * PI_F * (float)p / (float)NH;
                v = make_float2(cosf(a), sinf(a));
            }
            twr[tid] = v;
        }
        if (tid < NH * 14) {
            int h = tid / 14, b = tid % 14;
            float2 v = make_float2(0.f, 0.f);
            if (b < 13) {
                int p = (h * b) % NH;
                float a = 2.f * PI_F * (float)p / (float)NH;
                v = make_float2(cosf(a), sinf(a));
            }
            twb[tid] = v;
        }
        if (tid < 31 * 64) {
            int q = tid / 64 + 1, ow = tid % 64;
            int p = (q * ow) & 63;
            float a = 2.f * PI_F * (float)p / (float)NWOUT;
            twi[tid] = make_float2(cosf(a), sinf(a));
        }
    } else if (blk < 46) {
        int tid = (blk - 10) * 256 + threadIdx.x;
        if (tid < 9 * NF * NC) {
            int dd = tid / 1024;
            int f = (tid / 32) % 32;
            int c = tid % 32;
            float v = w[((size_t)dd * NC + c) * NF + f];
            unsigned short h = f2bf(v);
            wBh[tid] = h;
            wBl[tid] = f2bf(v - bf2f(h));
        }
    } else {
        __shared__ float2 tw[NH];
        int tid = threadIdx.x;
        if (tid < NH) {
            float a = -2.f * PI_F * (float)tid / (float)NH;
            tw[tid] = make_float2(cosf(a), sinf(a));
        }
        __syncthreads();
        int idx = (blk - 46) * 256 + tid;
        if (idx >= NH * NWR * NC) return;
        int c = idx % NC;
        int rem = idx / NC;
        int wr = rem % NWR;
        int h = rem / NWR;
        float ker = 0, kei = 0, kir = 0, kii = 0;
        int prow = (25 * (h + wr)) % NH;
        for (int i = 0; i < NKS; ++i) {
            int p = prow;
            for (int j = 0; j < NKS; ++j) {
                float2 e = tw[p];
                float ve = kexc[(i * NKS + j) * NC + c];
                float vi = kinh[(i * NKS + j) * NC + c];
                ker = fmaf(ve, e.x, ker); kei = fmaf(ve, e.y, kei);
                kir = fmaf(vi, e.x, kir); kii = fmaf(vi, e.y, kii);
                p += wr; if (p >= NH) p -= NH;
            }
            prow += h; if (prow >= NH) prow -= NH;
        }
        KE[idx] = make_float2(ker, kei);
        KI[idx] = make_float2(kir, kii);
    }
}

// ---------------- Kernel A: conv3x3 stride2 SAME + bias + gelu via MFMA
__global__ __launch_bounds__(256) void conv_mfma_kernel(
    const float* __restrict__ x, const unsigned short* __restrict__ wBh,
    const unsigned short* __restrict__ wBl, const float* __restrict__ bias,
    float* __restrict__ partial)
{
    __shared__ unsigned short aH[3 * 68 * 36];
    __shared__ unsigned short aL[3 * 68 * 36];
    int blk = blockIdx.x;              // (b*NT+t)*NHP + i
    int i = blk % NHP;
    int bt = blk / NHP;
    int tid = threadIdx.x;
    int l = tid & 63;
    int w = tid >> 6;

    int nt = w & 1;
    int fcol = nt * 16 + (l & 15);
    int c0 = (l >> 4) * 8;
    bf16x8 bh[9], bl[9];
    #pragma unroll
    for (int dd = 0; dd < 9; ++dd) {
        bh[dd] = *(const bf16x8*)(wBh + dd * 1024 + fcol * 32 + c0);
        bl[dd] = *(const bf16x8*)(wBl + dd * 1024 + fcol * 32 + c0);
    }

    const float* xb = x + (size_t)bt * (NH * NW * NC);
    for (int q = tid; q < 3 * 68 * 8; q += 256) {
        int r = q / 544;
        int k = q % 544;
        int pcol = k >> 3;
        int c4 = (k & 7) * 4;
        int gr = 2 * i - 1 + r;
        int gcol = pcol - 1;
        float4 v = make_float4(0.f, 0.f, 0.f, 0.f);
        if (gr >= 0 && gr < NH && gcol >= 0 && gcol < NW)
            v = *(const float4*)(xb + ((size_t)gr * NW + gcol) * NC + c4);
        int base = (r * 68 + pcol) * 36 + c4;
        unsigned short h0 = f2bf(v.x), h1 = f2bf(v.y), h2 = f2bf(v.z), h3 = f2bf(v.w);
        s16x4 th = {(short)h0, (short)h1, (short)h2, (short)h3};
        *(s16x4*)(aH + base) = th;
        s16x4 tl = {(short)f2bf(v.x - bf2f(h0)), (short)f2bf(v.y - bf2f(h1)),
                    (short)f2bf(v.z - bf2f(h2)), (short)f2bf(v.w - bf2f(h3))};
        *(s16x4*)(aL + base) = tl;
    }
    __syncthreads();

    float bv = bias[fcol];
    f32x4 acc0 = {bv, bv, bv, bv};
    f32x4 acc1 = {bv, bv, bv, bv};
    const int mtA = (w >> 1) ? 1 : 0;
    const bool hasB = (w >> 1) == 0;
    int m15 = l & 15;

    #pragma unroll
    for (int dd = 0; dd < 9; ++dd) {
        const int di = dd / 3, dj = dd % 3;
        {
            int pcol = 2 * (mtA * 16 + m15) + dj;
            int off = (di * 68 + pcol) * 36 + c0;
            FragU ah, al;
            ah.h[0] = *(const s16x4*)(aH + off);
            ah.h[1] = *(const s16x4*)(aH + off + 4);
            al.h[0] = *(const s16x4*)(aL + off);
            al.h[1] = *(const s16x4*)(aL + off + 4);
            acc0 = __builtin_amdgcn_mfma_f32_16x16x32_bf16(al.v, bh[dd], acc0, 0, 0, 0);
            acc0 = __builtin_amdgcn_mfma_f32_16x16x32_bf16(ah.v, bl[dd], acc0, 0, 0, 0);
            acc0 = __builtin_amdgcn_mfma_f32_16x16x32_bf16(ah.v, bh[dd], acc0, 0, 0, 0);
        }
        if (hasB) {
            int pcol = 2 * (32 + m15) + dj;
            if (pcol > 67) pcol = 67;
            int off = (di * 68 + pcol) * 36 + c0;
            FragU ah, al;
            ah.h[0] = *(const s16x4*)(aH + off);
            ah.h[1] = *(const s16x4*)(aH + off + 4);
            al.h[0] = *(const s16x4*)(aL + off);
            al.h[1] = *(const s16x4*)(aL + off + 4);
            acc1 = __builtin_amdgcn_mfma_f32_16x16x32_bf16(al.v, bh[dd], acc1, 0, 0, 0);
            acc1 = __builtin_amdgcn_mfma_f32_16x16x32_bf16(ah.v, bl[dd], acc1, 0, 0, 0);
            acc1 = __builtin_amdgcn_mfma_f32_16x16x32_bf16(ah.v, bh[dd], acc1, 0, 0, 0);
        }
    }

    float* pout = partial + (size_t)blk * (NWP * NF);
    int g4 = (l >> 4) * 4;
    #define GELU(v) (0.5f * (v) * (1.f + tanhf(0.7978845608028654f * ((v) + 0.044715f * (v) * (v) * (v)))))
    #pragma unroll
    for (int r = 0; r < 4; ++r) {
        float v = acc0[r];
        pout[(mtA * 16 + g4 + r) * NF + fcol] = GELU(v);
    }
    if (hasB && g4 == 0) {
        float v = acc1[0];
        pout[32 * NF + fcol] = GELU(v);
    }
    #undef GELU
}

// ---------------- ctx reduce stage 1
__global__ __launch_bounds__(256) void ctx_reduce1_kernel(
    const float* __restrict__ partial, float* __restrict__ red2)
{
    __shared__ float red[4][64];
    int blk = blockIdx.x;
    int b = blk / 136;
    int rem = blk % 136;
    int chunk = rem / 8;
    int ts = rem % 8;
    int lane = threadIdx.x & 63;
    int tig = threadIdx.x >> 6;
    int jf = chunk * 64 + lane;
    float s0 = 0.f, s1 = 0.f, s2 = 0.f;
    if (jf < NWP * NF) {
        const float* p = partial + (size_t)b * (NT * NHP) * (NWP * NF)
                       + (size_t)(ts * 132 + tig * 33) * (NWP * NF) + jf;
        #pragma unroll 3
        for (int s = 0; s < 33; s += 3) {
            s0 += p[(size_t)s * (NWP * NF)];
            s1 += p[(size_t)(s + 1) * (NWP * NF)];
            s2 += p[(size_t)(s + 2) * (NWP * NF)];
        }
    }
    red[tig][lane] = s0 + s1 + s2;
    __syncthreads();
    if (threadIdx.x < 64) {
        float tot = red[0][threadIdx.x] + red[1][threadIdx.x] +
                    red[2][threadIdx.x] + red[3][threadIdx.x];
        red2[((b * 17 + chunk) * 8 + ts) * 64 + threadIdx.x] = tot;
    }
}

// ---------------- ctx reduce stage 2 + gates (fused)
// 34 blocks (b, chunk of 2 j). Finish the reduction into LDS, then compute the
// 4 gate outputs for this block's 2 j values: thread = (gate, j_local, c).
__global__ __launch_bounds__(256) void ctx2_gate_kernel(
    const float* __restrict__ red2,
    const float* __restrict__ wA, const float* __restrict__ bA,
    const float* __restrict__ wD, const float* __restrict__ bD,
    const float* __restrict__ wM, const float* __restrict__ bM,
    const float* __restrict__ wG, const float* __restrict__ bG,
    float* __restrict__ alpha, float* __restrict__ delta,
    float* __restrict__ mu, float* __restrict__ gamma)
{
    __shared__ float red[4][64];
    __shared__ float ctxs[64];
    int b = blockIdx.x / 17, chunk = blockIdx.x % 17;
    int lane = threadIdx.x & 63, tg = threadIdx.x >> 6;
    const float* r2 = red2 + ((size_t)(b * 17 + chunk) * 8) * 64;
    float v = r2[(2 * tg) * 64 + lane] + r2[(2 * tg + 1) * 64 + lane];
    red[tg][lane] = v;
    __syncthreads();
    if (threadIdx.x < 64) {
        int jf = chunk * 64 + threadIdx.x;
        float tot = 0.f;
        if (jf < NWP * NF)
            tot = (red[0][threadIdx.x] + red[1][threadIdx.x] +
                   red[2][threadIdx.x] + red[3][threadIdx.x]) * (1.f / (NT * NHP));
        ctxs[threadIdx.x] = tot;
    }
    __syncthreads();

    int g = threadIdx.x >> 6;          // 0..3 gate type
    int jl = (threadIdx.x >> 5) & 1;   // 0..1 local j
    int c = threadIdx.x & 31;
    int j = chunk * 2 + jl;
    if (j < NWP) {
        const float* W  = (g == 0) ? wA : (g == 1) ? wD : (g == 2) ? wM : wG;
        const float* Bv = (g == 0) ? bA : (g == 1) ? bD : (g == 2) ? bM : bG;
        float s = Bv[c];
        #pragma unroll
        for (int f = 0; f < NF; ++f)
            s = fmaf(ctxs[jl * 32 + f], W[f * NC + c], s);
        float r;
        if (g < 2) r = 1.f / (1.f + expf(-s));
        else       r = fmaxf(s, 0.f) + log1pf(expf(-fabsf(s)));
        float* outp = (g == 0) ? alpha : (g == 1) ? delta : (g == 2) ? mu : gamma;
        outp[(b * NWP + j) * NC + c] = r;
    }
}

// ---------------- Kernel D: rDFT along W (65 -> 33), 4 h-rows per block
__global__ __launch_bounds__(256) void dft_rows_kernel(
    const float* __restrict__ x, const float2* __restrict__ twr_g,
    float2* __restrict__ U1)
{
    __shared__ __align__(16) float row[4][NW * NC];   // 33.3 KB
    __shared__ __align__(16) float2 twt[NH * 36];     // 18.7 KB
    int tid = threadIdx.x;
    int blk = blockIdx.x;           // bt*17 + grp
    int grp = blk % 17;
    int bt = blk / 17;
    int hbase = grp * 4;
    int nrows = NH - hbase; if (nrows > 4) nrows = 4;

    const float* xp = x + ((size_t)bt * NH + hbase) * (NW * NC);
    for (int idx = tid; idx < nrows * NW * NC; idx += 256) ((float*)row)[idx] = xp[idx];
    for (int idx = tid; idx < NH * 36; idx += 256) twt[idx] = twr_g[idx];
    __syncthreads();

    int c = tid & 31;
    int jg = tid >> 5;
    float2 acc[4][4];
    #pragma unroll
    for (int r = 0; r < 4; ++r)
        #pragma unroll
        for (int k = 0; k < 4; ++k) acc[r][k] = make_float2(0.f, 0.f);

    const float2* tp = twt + 4 * jg;
    #pragma unroll 5
    for (int q = 0; q < NW; ++q) {
        float4 e01 = *(const float4*)&tp[q * 36];
        float4 e23 = *(const float4*)&tp[q * 36 + 2];
        #pragma unroll
        for (int r = 0; r < 4; ++r) {
            float v = row[r][q * NC + c];
            acc[r][0].x = fmaf(v, e01.x, acc[r][0].x); acc[r][0].y = fmaf(v, e01.y, acc[r][0].y);
            acc[r][1].x = fmaf(v, e01.z, acc[r][1].x); acc[r][1].y = fmaf(v, e01.w, acc[r][1].y);
            acc[r][2].x = fmaf(v, e23.x, acc[r][2].x); acc[r][2].y = fmaf(v, e23.y, acc[r][2].y);
            acc[r][3].x = fmaf(v, e23.z, acc[r][3].x); acc[r][3].y = fmaf(v, e23.w, acc[r][3].y);
        }
    }
    #pragma unroll
    for (int r = 0; r < 4; ++r) {
        if (r < nrows) {
            float2* up = U1 + ((size_t)bt * NH + hbase + r) * (NWR * NC);
            up[(4 * jg + 0) * NC + c] = acc[r][0];
            up[(4 * jg + 1) * NC + c] = acc[r][1];
            up[(4 * jg + 2) * NC + c] = acc[r][2];
            up[(4 * jg + 3) * NC + c] = acc[r][3];
        }
    }
    if (jg == 0) {   // wr = 32
        float2 a32[4];
        #pragma unroll
        for (int r = 0; r < 4; ++r) a32[r] = make_float2(0.f, 0.f);
        #pragma unroll 5
        for (int q = 0; q < NW; ++q) {
            float2 e = twt[q * 36 + 32];
            #pragma unroll
            for (int r = 0; r < 4; ++r) {
                float v = row[r][q * NC + c];
                a32[r].x = fmaf(v, e.x, a32[r].x);
                a32[r].y = fmaf(v, e.y, a32[r].y);
            }
        }
        #pragma unroll
        for (int r = 0; r < 4; ++r)
            if (r < nrows)
                U1[((size_t)bt * NH + hbase + r) * (NWR * NC) + 32 * NC + c] = a32[r];
    }
}

// ---------------- 5-point DFT helper (compile-time twiddles)
template <int SIGN>
__device__ inline void compute5(const float2 v[5], float2* outp) {
    const float C5[5] = {1.f, 0.30901699437494742f, -0.80901699437494745f,
                         -0.80901699437494745f, 0.30901699437494742f};
    const float S5[5] = {0.f, 0.95105651629515357f, 0.58778525229247314f,
                         -0.58778525229247314f, -0.95105651629515357f};
    #pragma unroll
    for (int r = 0; r < 5; ++r) {
        float re = 0.f, im = 0.f;
        #pragma unroll
        for (int a = 0; a < 5; ++a) {
            const int m = (r * a) % 5;
            const float ex = C5[m];
            const float ey = (float)SIGN * S5[m];
            re = fmaf(v[a].x, ex, fmaf(-v[a].y, ey, re));
            im = fmaf(v[a].x, ey, fmaf(v[a].y, ex, im));
        }
        outp[r * NC] = make_float2(re, im);
    }
}

// ---------------- Kernel E/G: 65-pt DFT along H via CT 5x13, table stage-B
template <int SIGN, bool SCALE>
__global__ __launch_bounds__(256) void dft_cols_kernel(
    const float2* __restrict__ in, float2* __restrict__ out,
    const float2* __restrict__ twb_g)
{
    __shared__ __align__(16) float2 col[NH * NC];
    __shared__ __align__(16) float2 twb[NH * 14];
    int tid = threadIdx.x;
    int blk = blockIdx.x;
    int wr = blk % NWR;
    int bt = blk / NWR;
    const float2* ip = in + ((size_t)bt * NH) * (NWR * NC) + wr * NC;
    for (int idx = tid; idx < NH * NC; idx += 256) {
        int p = idx >> 5, c = idx & 31;
        col[idx] = ip[(size_t)p * (NWR * NC) + c];
    }
    for (int idx = tid; idx < NH * 14; idx += 256) twb[idx] = twb_g[idx];
    __syncthreads();

    float2 va0[5], va1[5];
    int bq0 = tid >> 5, c0 = tid & 31;
    int q1 = tid + 256;
    int bq1 = q1 >> 5, c1 = q1 & 31;
    #pragma unroll
    for (int a = 0; a < 5; ++a) {
        va0[a] = col[(13 * a + bq0) * NC + c0];
        if (q1 < 416) va1[a] = col[(13 * a + bq1) * NC + c1];
    }
    __syncthreads();
    compute5<SIGN>(va0, &col[(bq0 * 5) * NC + c0]);
    if (q1 < 416) compute5<SIGN>(va1, &col[(bq1 * 5) * NC + c1]);
    __syncthreads();

    const float S = (float)SIGN;
    int c = tid & 31;
    int h0 = tid >> 5;
    const float s = SCALE ? (1.f / (float)NH) : 1.f;
    float2* op = out + ((size_t)bt * NH) * (NWR * NC) + wr * NC;
    float2 acc[8];
    #pragma unroll
    for (int k = 0; k < 8; ++k) {
        int h = h0 + 8 * k;
        int r = h % 5;
        const float2* Ap = col + r * NC + c;
        const float2* tp = twb + h * 14;
        float re = 0.f, im = 0.f;
        #pragma unroll
        for (int p = 0; p < 6; ++p) {
            float4 tq = *(const float4*)&tp[2 * p];
            float2 v0 = Ap[(2 * p) * 5 * NC];
            float2 v1 = Ap[(2 * p + 1) * 5 * NC];
            re = fmaf(v0.x, tq.x, fmaf(-S * v0.y, tq.y, re));
            im = fmaf(S * v0.x, tq.y, fmaf(v0.y, tq.x, im));
            re = fmaf(v1.x, tq.z, fmaf(-S * v1.y, tq.w, re));
            im = fmaf(S * v1.x, tq.w, fmaf(v1.y, tq.z, im));
        }
        {
            float2 t12 = tp[12];
            float2 v = Ap[12 * 5 * NC];
            re = fmaf(v.x, t12.x, fmaf(-S * v.y, t12.y, re));
            im = fmaf(S * v.x, t12.y, fmaf(v.y, t12.x, im));
        }
        acc[k] = make_float2(re * s, im * s);
    }
    #pragma unroll
    for (int k = 0; k < 8; ++k) {
        int h = h0 + 8 * k;
        op[(size_t)h * (NWR * NC) + c] = acc[k];
    }
    if (h0 == 0) {   // h = 64, r = 4
        const float2* Ap = col + 4 * NC + c;
        const float2* tp = twb + 64 * 14;
        float re = 0.f, im = 0.f;
        #pragma unroll
        for (int p = 0; p < 6; ++p) {
            float4 tq = *(const float4*)&tp[2 * p];
            float2 v0 = Ap[(2 * p) * 5 * NC];
            float2 v1 = Ap[(2 * p + 1) * 5 * NC];
            re = fmaf(v0.x, tq.x, fmaf(-S * v0.y, tq.y, re));
            im = fmaf(S * v0.x, tq.y, fmaf(v0.y, tq.x, im));
            re = fmaf(v1.x, tq.z, fmaf(-S * v1.y, tq.w, re));
            im = fmaf(S * v1.x, tq.w, fmaf(v1.y, tq.z, im));
        }
        {
            float2 t12 = tp[12];
            float2 v = Ap[12 * 5 * NC];
            re = fmaf(v.x, t12.x, fmaf(-S * v.y, t12.y, re));
            im = fmaf(S * v.x, t12.y, fmaf(v.y, t12.x, im));
        }
        op[(size_t)64 * (NWR * NC) + c] = make_float2(re * s, im * s);
    }
}

// ---------------- Kernel F: SSM scan over T
__global__ __launch_bounds__(256) void scan_kernel(
    float2* __restrict__ buf, const float2* __restrict__ KE,
    const float2* __restrict__ KI, const float* __restrict__ alpha,
    const float* __restrict__ delta, const float* __restrict__ mu,
    const float* __restrict__ gamma)
{
    int idx = blockIdx.x * 256 + threadIdx.x;
    if (idx >= NB * NH * NWR * NC) return;
    int c = idx % NC;
    int rem = idx / NC;
    int wr = rem % NWR;
    int rem2 = rem / NWR;
    int h = rem2 % NH;
    int b = rem2 / NH;

    int gi = (b * NWP + wr) * NC + c;
    float axx = 0.9f * alpha[gi];
    float ayy = 0.9f * delta[gi];
    float m = mu[gi], g = gamma[gi];
    float2 ki = KI[(h * NWR + wr) * NC + c];
    float2 ke = KE[(h * NWR + wr) * NC + c];
    float2 axy = make_float2(-ki.x * m, -ki.y * m);
    float2 ayx = make_float2(ke.x * g, ke.y * g);

    float2 xs = make_float2(0.f, 0.f), ys = make_float2(0.f, 0.f);
    size_t base = ((size_t)b * NT) * NH * NWR * NC + (size_t)h * (NWR * NC) + wr * NC + c;
    const size_t stride = (size_t)NH * NWR * NC;
    for (int t = 0; t < NT; ++t) {
        float2 U = buf[base + (size_t)t * stride];
        float2 nx, ny;
        nx.x = fmaf(axx, xs.x, fmaf(axy.x, ys.x, fmaf(-axy.y, ys.y, U.x)));
        nx.y = fmaf(axx, xs.y, fmaf(axy.x, ys.y, fmaf(axy.y, ys.x, U.y)));
        ny.x = fmaf(ayx.x, xs.x, fmaf(-ayx.y, xs.y, ayy * ys.x));
        ny.y = fmaf(ayx.x, xs.y, fmaf(ayx.y, xs.x, ayy * ys.y));
        xs = nx; ys = ny;
        buf[base + (size_t)t * stride] = ys;
    }
}

// ---------------- Kernel H: irfft along W (33 -> 64), 4 h-rows per block
__global__ __launch_bounds__(256) void irfft_w_kernel(
    const float2* __restrict__ Z, const float2* __restrict__ twi_g,
    float* __restrict__ out)
{
    __shared__ __align__(16) float2 z[4][NWR * NC];   // 33.8 KB
    __shared__ __align__(16) float2 twi[31 * 64];     // 15.9 KB
    int tid = threadIdx.x;
    int blk = blockIdx.x;           // bt*17 + grp
    int grp = blk % 17;
    int bt = blk / 17;
    int hbase = grp * 4;
    int nrows = NH - hbase; if (nrows > 4) nrows = 4;

    const float2* zp = Z + ((size_t)bt * NH + hbase) * (NWR * NC);
    for (int idx = tid; idx < nrows * NWR * NC; idx += 256) ((float2*)z)[idx] = zp[idx];
    for (int idx = tid; idx < 31 * 64; idx += 256) twi[idx] = twi_g[idx];
    __syncthreads();

    int c = tid & 31;
    int g = tid >> 5;
    float acc[4][8];
    #pragma unroll
    for (int r = 0; r < 4; ++r) {
        float z0 = z[r][c].x;
        float zn = z[r][32 * NC + c].x;
        #pragma unroll
        for (int m = 0; m < 8; ++m) acc[r][m] = z0 + ((m & 1) ? -zn : zn);
    }
    const float2* tp = twi + 8 * g;
    for (int q = 1; q < 32; ++q) {
        const float4* tq = (const float4*)&tp[(q - 1) * 64];
        float4 e0 = tq[0], e1 = tq[1], e2 = tq[2], e3 = tq[3];
        #pragma unroll
        for (int r = 0; r < 4; ++r) {
            float2 v = z[r][q * NC + c];
            float vx = 2.f * v.x, vy = 2.f * v.y;
            acc[r][0] = fmaf(vx, e0.x, fmaf(-vy, e0.y, acc[r][0]));
            acc[r][1] = fmaf(vx, e0.z, fmaf(-vy, e0.w, acc[r][1]));
            acc[r][2] = fmaf(vx, e1.x, fmaf(-vy, e1.y, acc[r][2]));
            acc[r][3] = fmaf(vx, e1.z, fmaf(-vy, e1.w, acc[r][3]));
            acc[r][4] = fmaf(vx, e2.x, fmaf(-vy, e2.y, acc[r][4]));
            acc[r][5] = fmaf(vx, e2.z, fmaf(-vy, e2.w, acc[r][5]));
            acc[r][6] = fmaf(vx, e3.x, fmaf(-vy, e3.y, acc[r][6]));
            acc[r][7] = fmaf(vx, e3.z, fmaf(-vy, e3.w, acc[r][7]));
        }
    }
    #pragma unroll
    for (int r = 0; r < 4; ++r) {
        if (r < nrows) {
            float* op = out + ((size_t)bt * NH + hbase + r) * (NWOUT * NC);
            #pragma unroll
            for (int m = 0; m < 8; ++m)
                op[(8 * g + m) * NC + c] = acc[r][m] * (1.f / (float)NWOUT);
        }
    }
}

extern "C" void kernel_launch(void* const* d_in, const int* in_sizes, int n_in,
                              void* d_out, int out_size, void* d_ws, size_t ws_size,
                              hipStream_t stream)
{
    const float* x     = (const float*)d_in[0];
    const float* convw = (const float*)d_in[1];
    const float* convb = (const float*)d_in[2];
    const float* wA = (const float*)d_in[3];
    const float* bA = (const float*)d_in[4];
    const float* wD = (const float*)d_in[5];
    const float* bD = (const float*)d_in[6];
    const float* wM = (const float*)d_in[7];
    const float* bM = (const float*)d_in[8];
    const float* wG = (const float*)d_in[9];
    const float* bG = (const float*)d_in[10];
    const float* kexc = (const float*)d_in[11];
    const float* kinh = (const float*)d_in[12];

    const size_t NBIG = (size_t)NB * NT * NH * NWR * NC;
    char* ws = (char*)d_ws;
    float2* bufA    = (float2*)ws;  ws += NBIG * sizeof(float2);
    float2* KE      = (float2*)ws;  ws += (size_t)NH * NWR * NC * sizeof(float2);
    float2* KI      = (float2*)ws;  ws += (size_t)NH * NWR * NC * sizeof(float2);
    float*  partial = (float*)ws;   ws += (size_t)NB * (NT * NHP) * (NWP * NF) * sizeof(float);
    float*  red2    = (float*)ws;   ws += (size_t)NB * 17 * 8 * 64 * sizeof(float);
    float*  alpha   = (float*)ws;   ws += (size_t)NB * NWP * NC * sizeof(float);
    float*  delta   = (float*)ws;   ws += (size_t)NB * NWP * NC * sizeof(float);
    float*  mu      = (float*)ws;   ws += (size_t)NB * NWP * NC * sizeof(float);
    float*  gamma   = (float*)ws;   ws += (size_t)NB * NWP * NC * sizeof(float);
    float2* TWR     = (float2*)ws;  ws += (size_t)NH * 36 * sizeof(float2);
    float2* TWB     = (float2*)ws;  ws += (size_t)NH * 14 * sizeof(float2);
    float2* TWI     = (float2*)ws;  ws += (size_t)31 * 64 * sizeof(float2);
    unsigned short* wBh = (unsigned short*)ws; ws += (size_t)9 * NC * NF * sizeof(unsigned short);
    unsigned short* wBl = (unsigned short*)ws; ws += (size_t)9 * NC * NF * sizeof(unsigned short);

    const int specBlocks = (NH * NWR * NC + 255) / 256;   // 269
    setup_kernel<<<46 + specBlocks, 256, 0, stream>>>(
        convw, wBh, wBl, TWR, TWB, TWI, kexc, kinh, KE, KI);

    conv_mfma_kernel<<<NB * NT * NHP, 256, 0, stream>>>(x, wBh, wBl, convb, partial);
    ctx_reduce1_kernel<<<NB * 136, 256, 0, stream>>>(partial, red2);
    ctx2_gate_kernel<<<NB * 17, 256, 0, stream>>>(
        red2, wA, bA, wD, bD, wM, bM, wG, bG, alpha, delta, mu, gamma);

    dft_rows_kernel<<<NB * NT * 17, 256, 0, stream>>>(x, TWR, bufA);
    dft_cols_kernel<-1, false><<<NB * NT * NWR, 256, 0, stream>>>(bufA, bufA, TWB);

    scan_kernel<<<(NB * NH * NWR * NC + 255) / 256, 256, 0, stream>>>(
        bufA, KE, KI, alpha, delta, mu, gamma);

    dft_cols_kernel<+1, true><<<NB * NT * NWR, 256, 0, stream>>>(bufA, bufA, TWB);
    irfft_w_kernel<<<NB * NT * 17, 256, 0, stream>>>(bufA, TWI, (float*)d_out);
}